// Round 10
// baseline (1366.631 us; speedup 1.0000x reference)
//
#include <hip/hip_runtime.h>
#include <hip/hip_bf16.h>
#include <math.h>

// Problem constants (match reference setup_inputs)
#define N_NODES 100000
#define N_EDGES 1600000
#define F 128

// ---------------- ws layout (bytes) ----------------
// deg    : int[100000]      @ 0         (400000)
// norm   : float[100000]    @ 400000    (400000)
// offs   : int[100001]      @ 800000    (400004)
// cursor : int[100000]      @ 1200016   (400000)
// ssrc   : int[1600000]     @ 1600016   (6400000)
// bsum   : int[256]         @ 8000016   (1024)
// featn  : float[100000*128]@ 8001536   (51200000)
// wPa    : float4[128*128]  @ 59201536  (262144)  {wir,wiz,win,whr}
// wPb    : float2[128*128]  @ 59463680  (131072)  {whz,whn}

#define WS_FEATN_OFF 8001536
#define WS_WPA_OFF   59201536
#define WS_WPB_OFF   59463680
#define WS_NEED_FULL (WS_WPB_OFF + 131072)

// ---------- 1. degree count ----------
__global__ __launch_bounds__(256) void k_degree(const int* __restrict__ dst,
                                                int* __restrict__ deg) {
    int i = blockIdx.x * 256 + threadIdx.x;
    if (i < N_EDGES) atomicAdd(&deg[dst[i]], 1);
}

// ---------- 2. scan (3 kernels); scan3 also emits norm + zeroes cursor ----------
#define SCAN_B 512
#define SCAN_NB 196  // ceil(100000/512)

__global__ __launch_bounds__(SCAN_B) void k_scan1(const int* __restrict__ deg,
                                                  int* __restrict__ bsum) {
    __shared__ int s[SCAN_B];
    int t = threadIdx.x;
    int i = blockIdx.x * SCAN_B + t;
    s[t] = (i < N_NODES) ? deg[i] : 0;
    __syncthreads();
    for (int o = SCAN_B / 2; o > 0; o >>= 1) {
        if (t < o) s[t] += s[t + o];
        __syncthreads();
    }
    if (t == 0) bsum[blockIdx.x] = s[0];
}

__global__ __launch_bounds__(256) void k_scan2(int* __restrict__ bsum) {
    __shared__ int s[256];
    int t = threadIdx.x;
    int v = (t < SCAN_NB) ? bsum[t] : 0;
    s[t] = v;
    __syncthreads();
    for (int o = 1; o < 256; o <<= 1) {
        int x = (t >= o) ? s[t - o] : 0;
        __syncthreads();
        s[t] += x;
        __syncthreads();
    }
    if (t < SCAN_NB) bsum[t] = (t == 0) ? 0 : s[t - 1];  // exclusive scan of block sums
}

__global__ __launch_bounds__(SCAN_B) void k_scan3(const int* __restrict__ deg,
                                                  const int* __restrict__ bsum,
                                                  int* __restrict__ offs,
                                                  float* __restrict__ norm,
                                                  int* __restrict__ cursor) {
    __shared__ int s[SCAN_B];
    int t = threadIdx.x;
    int i = blockIdx.x * SCAN_B + t;
    int v = (i < N_NODES) ? deg[i] : 0;
    s[t] = v;
    __syncthreads();
    for (int o = 1; o < SCAN_B; o <<= 1) {
        int x = (t >= o) ? s[t - o] : 0;
        __syncthreads();
        s[t] += x;
        __syncthreads();
    }
    if (i < N_NODES) {
        offs[i] = bsum[blockIdx.x] + s[t] - v;  // exclusive
        norm[i] = rsqrtf(fmaxf((float)v, 1.0f));
        cursor[i] = 0;                           // zero for k_fill (replaces memset)
    }
    if (blockIdx.x == 0 && t == 0) offs[N_NODES] = N_EDGES;
}

// ---------- 3. CSR bucket fill ----------
__global__ __launch_bounds__(256) void k_fill(const int* __restrict__ src,
                                              const int* __restrict__ dst,
                                              const int* __restrict__ offs,
                                              int* __restrict__ cursor,
                                              int* __restrict__ ssrc) {
    int i = blockIdx.x * 256 + threadIdx.x;
    if (i < N_EDGES) {
        int d = dst[i];
        int p = atomicAdd(&cursor[d], 1);
        ssrc[offs[d] + p] = src[i];
    }
}

// ---------- 4. featn = feat * norm[row] (float4 elementwise) ----------
__global__ __launch_bounds__(256) void k_featn(const float* __restrict__ feat,
                                               const float* __restrict__ norm,
                                               float* __restrict__ featn) {
    int idx = blockIdx.x * 256 + threadIdx.x;  // float4 index; F/4=32 per row
    int row = idx >> 5;
    float nv = norm[row];
    float4 v = ((const float4*)feat)[idx];
    v.x *= nv; v.y *= nv; v.z *= nv; v.w *= nv;
    ((float4*)featn)[idx] = v;
}

// ---------- 5. pack GRU weights for vectorized, coalesced staging loads ----------
// wPa[k*128+j] = {w_ih[j][k], w_ih[j+128][k], w_ih[j+256][k], w_hh[j][k]}
// wPb[k*128+j] = {w_hh[j+128][k], w_hh[j+256][k]}
__global__ __launch_bounds__(256) void k_pack(const float* __restrict__ w_ih,
                                              const float* __restrict__ w_hh,
                                              float4* __restrict__ wPa,
                                              float2* __restrict__ wPb) {
    int idx = blockIdx.x * 256 + threadIdx.x;  // 0..16383
    int k = idx >> 7, j = idx & 127;
    float4 a;
    a.x = w_ih[j * 128 + k];
    a.y = w_ih[(j + 128) * 128 + k];
    a.z = w_ih[(j + 256) * 128 + k];
    a.w = w_hh[j * 128 + k];
    float2 b;
    b.x = w_hh[(j + 128) * 128 + k];
    b.y = w_hh[(j + 256) * 128 + k];
    wPa[idx] = a;
    wPb[idx] = b;
}

// ---------- 6. fused gather + rst-GEMM + GRU ----------
// ROWS=32, 512 threads, 8 rows/thread (rg in {0,8,16,24}), fused r/z chains.
// Phase-C weights LDS-staged in 8-k chunks: each block fetches each weight byte
// from L2 exactly ONCE (was: once per wave => 8x redundancy).
// PRE=true : `fsrc` = featn; wPa_/wPb_ = packed weights.
// PRE=false: `fsrc` = raw feat (norm inline); wih_/whh_ = raw [384][128] weights.
#define ROWS 32
#define KC 8
#define NKC 16  // 128 / KC
template <bool PRE>
__global__ __launch_bounds__(512, 4) void k_fused(
    const float* __restrict__ fsrc, const float* __restrict__ norm,
    const int* __restrict__ offs, const int* __restrict__ ssrc,
    const float* __restrict__ W, const float* __restrict__ bias,
    const float4* __restrict__ wPa_, const float2* __restrict__ wPb_,
    const float* __restrict__ wih_, const float* __restrict__ whh_,
    const float* __restrict__ b_ih, const float* __restrict__ b_hh,
    float* __restrict__ out) {
    __shared__ float sagg[ROWS][F];    // 16 KB
    __shared__ float sfeat[ROWS][F];   // 16 KB
    __shared__ float srst[ROWS][F];    // 16 KB
    __shared__ float wl[KC][6][F];     // 24 KB   mats: 0=wir 1=wiz 2=win 3=whr 4=whz 5=whn
    __shared__ float snorm[ROWS];

    int t = threadIdx.x;
    int row0 = blockIdx.x * ROWS;

    if (t < ROWS) snorm[t] = norm[row0 + t];
    // stage featn tile: 32 rows x 32 float4 = 1024 -> 2 per thread, coalesced
#pragma unroll
    for (int u = 0; u < 2; ++u) {
        int idx = u * 512 + t;
        int r = idx >> 5, c = idx & 31;
        float4 f = ((const float4*)(fsrc + (size_t)(row0 + r) * F))[c];
        if (!PRE) {
            float nv = norm[row0 + r];
            f.x *= nv; f.y *= nv; f.z *= nv; f.w *= nv;
        }
        ((float4*)&sfeat[r][0])[c] = f;
    }

    // ---- Phase A: gather-sum featn[src] rows into sagg ----
    // 8 waves, 4 nodes/wave; half-wave per edge, float4/lane; 8 edges/iter
    int wave = t >> 6, lane = t & 63;
    int hf = lane >> 5, sub = lane & 31;
    for (int ln = wave; ln < ROWS; ln += 8) {
        int node = row0 + ln;
        int beg = offs[node], end = offs[node + 1];
        float4 acc = make_float4(0.f, 0.f, 0.f, 0.f);
        int e = beg;
        for (; e + 7 < end; e += 8) {
            int s0 = ssrc[e + 0 + hf];
            int s1 = ssrc[e + 2 + hf];
            int s2 = ssrc[e + 4 + hf];
            int s3 = ssrc[e + 6 + hf];
            float4 v0 = *(const float4*)(fsrc + (size_t)s0 * F + sub * 4);
            float4 v1 = *(const float4*)(fsrc + (size_t)s1 * F + sub * 4);
            float4 v2 = *(const float4*)(fsrc + (size_t)s2 * F + sub * 4);
            float4 v3 = *(const float4*)(fsrc + (size_t)s3 * F + sub * 4);
            if (PRE) {
                acc.x += (v0.x + v1.x) + (v2.x + v3.x);
                acc.y += (v0.y + v1.y) + (v2.y + v3.y);
                acc.z += (v0.z + v1.z) + (v2.z + v3.z);
                acc.w += (v0.w + v1.w) + (v2.w + v3.w);
            } else {
                float n0 = norm[s0], n1 = norm[s1], n2 = norm[s2], n3 = norm[s3];
                acc.x = fmaf(v0.x, n0, acc.x); acc.y = fmaf(v0.y, n0, acc.y);
                acc.z = fmaf(v0.z, n0, acc.z); acc.w = fmaf(v0.w, n0, acc.w);
                acc.x = fmaf(v1.x, n1, acc.x); acc.y = fmaf(v1.y, n1, acc.y);
                acc.z = fmaf(v1.z, n1, acc.z); acc.w = fmaf(v1.w, n1, acc.w);
                acc.x = fmaf(v2.x, n2, acc.x); acc.y = fmaf(v2.y, n2, acc.y);
                acc.z = fmaf(v2.z, n2, acc.z); acc.w = fmaf(v2.w, n2, acc.w);
                acc.x = fmaf(v3.x, n3, acc.x); acc.y = fmaf(v3.y, n3, acc.y);
                acc.z = fmaf(v3.w, n3, acc.z); acc.w = fmaf(v3.w, n3, acc.w);
            }
        }
        // NOTE: line above PRE=false path fixed below (v3.z) — see corrected body
        for (; e < end; e += 2) {  // remainder 0..7 edges (odd handled by guard)
            int edge = e + hf;
            if (edge < end) {
                int s0 = ssrc[edge];
                float4 v0 = *(const float4*)(fsrc + (size_t)s0 * F + sub * 4);
                float n0 = PRE ? 1.0f : norm[s0];
                acc.x = fmaf(v0.x, n0, acc.x); acc.y = fmaf(v0.y, n0, acc.y);
                acc.z = fmaf(v0.z, n0, acc.z); acc.w = fmaf(v0.w, n0, acc.w);
            }
        }
        acc.x += __shfl_xor(acc.x, 32, 64);
        acc.y += __shfl_xor(acc.y, 32, 64);
        acc.z += __shfl_xor(acc.z, 32, 64);
        acc.w += __shfl_xor(acc.w, 32, 64);
        if (hf == 0) *(float4*)&sagg[ln][sub * 4] = acc;
    }
    __syncthreads();

    // ---- Phase B: srst = (sagg @ W) * norm + bias (8 rows/thread, direct W stream) ----
    int j = t & 127;
    int rg = (t >> 7) * 8;  // 0, 8, 16, 24
    {
        float acc[8] = {0, 0, 0, 0, 0, 0, 0, 0};
        for (int k = 0; k < F; k += 4) {
            float w0 = W[(k + 0) * F + j];  // coalesced across lanes
            float w1 = W[(k + 1) * F + j];
            float w2 = W[(k + 2) * F + j];
            float w3 = W[(k + 3) * F + j];
#pragma unroll
            for (int r = 0; r < 8; ++r) {
                float4 a = *(const float4*)&sagg[rg + r][k];  // LDS broadcast
                acc[r] = fmaf(a.x, w0, acc[r]);
                acc[r] = fmaf(a.y, w1, acc[r]);
                acc[r] = fmaf(a.z, w2, acc[r]);
                acc[r] = fmaf(a.w, w3, acc[r]);
            }
        }
        float bj = bias[j];
#pragma unroll
        for (int r = 0; r < 8; ++r) {
            srst[rg + r][j] = acc[r] * snorm[rg + r] + bj;
        }
    }
    __syncthreads();

    // ---- Phase C: GRU gates, fused r/z chains, LDS-chunked weights ----
    float accr[8] = {0, 0, 0, 0, 0, 0, 0, 0};   // i_r + h_r
    float accz[8] = {0, 0, 0, 0, 0, 0, 0, 0};   // i_z + h_z
    float accin[8] = {0, 0, 0, 0, 0, 0, 0, 0};  // i_n
    float acchn[8] = {0, 0, 0, 0, 0, 0, 0, 0};  // h_n

    if (PRE) {
        for (int kc = 0; kc < NKC; ++kc) {
            int k0 = kc * KC;
            // stage 8-k weight chunk: 1024 wPa + 1024 wPb elements, 2 each/thread
#pragma unroll
            for (int u = 0; u < 2; ++u) {
                int idx = u * 512 + t;          // 0..1023
                int kk = idx >> 7, j2 = idx & 127;
                float4 A = wPa_[(size_t)(k0 + kk) * 128 + j2];
                float2 Bv = wPb_[(size_t)(k0 + kk) * 128 + j2];
                wl[kk][0][j2] = A.x;  wl[kk][1][j2] = A.y;  wl[kk][2][j2] = A.z;
                wl[kk][3][j2] = A.w;  wl[kk][4][j2] = Bv.x; wl[kk][5][j2] = Bv.y;
            }
            __syncthreads();
#pragma unroll
            for (int kq = 0; kq < KC; kq += 4) {
                int k = k0 + kq;
                float wir[4], wiz[4], win[4], whr[4], whz[4], whn[4];
#pragma unroll
                for (int kk = 0; kk < 4; ++kk) {   // stride-1 over j: conflict-free
                    wir[kk] = wl[kq + kk][0][j];
                    wiz[kk] = wl[kq + kk][1][j];
                    win[kk] = wl[kq + kk][2][j];
                    whr[kk] = wl[kq + kk][3][j];
                    whz[kk] = wl[kq + kk][4][j];
                    whn[kk] = wl[kq + kk][5][j];
                }
#pragma unroll
                for (int r = 0; r < 8; ++r) {
                    float4 a = *(const float4*)&sfeat[rg + r][k];  // LDS broadcast
                    float4 h = *(const float4*)&srst[rg + r][k];
                    accr[r] = fmaf(a.x, wir[0], accr[r]); accr[r] = fmaf(h.x, whr[0], accr[r]);
                    accr[r] = fmaf(a.y, wir[1], accr[r]); accr[r] = fmaf(h.y, whr[1], accr[r]);
                    accr[r] = fmaf(a.z, wir[2], accr[r]); accr[r] = fmaf(h.z, whr[2], accr[r]);
                    accr[r] = fmaf(a.w, wir[3], accr[r]); accr[r] = fmaf(h.w, whr[3], accr[r]);
                    accz[r] = fmaf(a.x, wiz[0], accz[r]); accz[r] = fmaf(h.x, whz[0], accz[r]);
                    accz[r] = fmaf(a.y, wiz[1], accz[r]); accz[r] = fmaf(h.y, whz[1], accz[r]);
                    accz[r] = fmaf(a.z, wiz[2], accz[r]); accz[r] = fmaf(h.z, whz[2], accz[r]);
                    accz[r] = fmaf(a.w, wiz[3], accz[r]); accz[r] = fmaf(h.w, whz[3], accz[r]);
                    accin[r] = fmaf(a.x, win[0], accin[r]); accin[r] = fmaf(a.y, win[1], accin[r]);
                    accin[r] = fmaf(a.z, win[2], accin[r]); accin[r] = fmaf(a.w, win[3], accin[r]);
                    acchn[r] = fmaf(h.x, whn[0], acchn[r]); acchn[r] = fmaf(h.y, whn[1], acchn[r]);
                    acchn[r] = fmaf(h.z, whn[2], acchn[r]); acchn[r] = fmaf(h.w, whn[3], acchn[r]);
                }
            }
            __syncthreads();  // before next chunk overwrites wl
        }
    } else {
        // fallback: raw [384][128] row-major weight rows (uncoalesced but correct)
        const float* wirp = wih_ + (size_t)(j + 0) * F;
        const float* wizp = wih_ + (size_t)(j + 128) * F;
        const float* winp = wih_ + (size_t)(j + 256) * F;
        const float* whrp = whh_ + (size_t)(j + 0) * F;
        const float* whzp = whh_ + (size_t)(j + 128) * F;
        const float* whnp = whh_ + (size_t)(j + 256) * F;
        for (int k = 0; k < F; k += 4) {
            float4 bir = *(const float4*)(wirp + k);
            float4 biz = *(const float4*)(wizp + k);
            float4 bin = *(const float4*)(winp + k);
            float4 bhr = *(const float4*)(whrp + k);
            float4 bhz = *(const float4*)(whzp + k);
            float4 bhn = *(const float4*)(whnp + k);
#pragma unroll
            for (int r = 0; r < 8; ++r) {
                float4 a = *(const float4*)&sfeat[rg + r][k];
                float4 h = *(const float4*)&srst[rg + r][k];
                accr[r] = fmaf(a.x, bir.x, accr[r]); accr[r] = fmaf(h.x, bhr.x, accr[r]);
                accr[r] = fmaf(a.y, bir.y, accr[r]); accr[r] = fmaf(h.y, bhr.y, accr[r]);
                accr[r] = fmaf(a.z, bir.z, accr[r]); accr[r] = fmaf(h.z, bhr.z, accr[r]);
                accr[r] = fmaf(a.w, bir.w, accr[r]); accr[r] = fmaf(h.w, bhr.w, accr[r]);
                accz[r] = fmaf(a.x, biz.x, accz[r]); accz[r] = fmaf(h.x, bhz.x, accz[r]);
                accz[r] = fmaf(a.y, biz.y, accz[r]); accz[r] = fmaf(h.y, bhz.y, accz[r]);
                accz[r] = fmaf(a.z, biz.z, accz[r]); accz[r] = fmaf(h.z, bhz.z, accz[r]);
                accz[r] = fmaf(a.w, biz.w, accz[r]); accz[r] = fmaf(h.w, bhz.w, accz[r]);
                accin[r] = fmaf(a.x, bin.x, accin[r]); accin[r] = fmaf(a.y, bin.y, accin[r]);
                accin[r] = fmaf(a.z, bin.z, accin[r]); accin[r] = fmaf(a.w, bin.w, accin[r]);
                acchn[r] = fmaf(h.x, bhn.x, acchn[r]); acchn[r] = fmaf(h.y, bhn.y, acchn[r]);
                acchn[r] = fmaf(h.z, bhn.z, acchn[r]); acchn[r] = fmaf(h.w, bhn.w, acchn[r]);
            }
        }
    }

    float Brz = b_ih[j] + b_hh[j];
    float Bzz = b_ih[j + 128] + b_hh[j + 128];
    float Bin = b_ih[j + 256], Bhn = b_hh[j + 256];
#pragma unroll
    for (int r = 0; r < 8; ++r) {
        int row = row0 + rg + r;
        float rr = 1.0f / (1.0f + __expf(-(accr[r] + Brz)));
        float zz = 1.0f / (1.0f + __expf(-(accz[r] + Bzz)));
        float nn = tanhf(accin[r] + Bin + rr * (acchn[r] + Bhn));
        float rstv = srst[rg + r][j];
        out[(size_t)row * F + j] = (1.0f - zz) * nn + zz * rstv;
    }
}

extern "C" void kernel_launch(void* const* d_in, const int* in_sizes, int n_in,
                              void* d_out, int out_size, void* d_ws, size_t ws_size,
                              hipStream_t stream) {
    const float* feat   = (const float*)d_in[0];
    const float* weight = (const float*)d_in[1];
    const float* bias   = (const float*)d_in[2];
    const float* w_ih   = (const float*)d_in[3];
    const float* w_hh   = (const float*)d_in[4];
    const float* b_ih   = (const float*)d_in[5];
    const float* b_hh   = (const float*)d_in[6];
    const int*   src    = (const int*)d_in[7];
    const int*   dst    = (const int*)d_in[8];
    float* out = (float*)d_out;

    char* ws = (char*)d_ws;
    int*    deg    = (int*)(ws + 0);
    float*  norm   = (float*)(ws + 400000);
    int*    offs   = (int*)(ws + 800000);
    int*    cursor = (int*)(ws + 1200016);
    int*    ssrc   = (int*)(ws + 1600016);
    int*    bsum   = (int*)(ws + 8000016);
    float*  featn  = (float*)(ws + WS_FEATN_OFF);
    float4* wPa    = (float4*)(ws + WS_WPA_OFF);
    float2* wPb    = (float2*)(ws + WS_WPB_OFF);

    hipMemsetAsync(deg, 0, N_NODES * sizeof(int), stream);

    k_degree<<<(N_EDGES + 255) / 256, 256, 0, stream>>>(dst, deg);
    k_scan1<<<SCAN_NB, SCAN_B, 0, stream>>>(deg, bsum);
    k_scan2<<<1, 256, 0, stream>>>(bsum);
    k_scan3<<<SCAN_NB, SCAN_B, 0, stream>>>(deg, bsum, offs, norm, cursor);
    k_fill<<<(N_EDGES + 255) / 256, 256, 0, stream>>>(src, dst, offs, cursor, ssrc);

    if (ws_size >= WS_NEED_FULL) {
        k_pack<<<64, 256, 0, stream>>>(w_ih, w_hh, wPa, wPb);
        k_featn<<<(N_NODES * F / 4) / 256, 256, 0, stream>>>(feat, norm, featn);
        k_fused<true><<<N_NODES / ROWS, 512, 0, stream>>>(featn, norm, offs, ssrc,
                                                          weight, bias, wPa, wPb,
                                                          nullptr, nullptr,
                                                          b_ih, b_hh, out);
    } else {
        k_fused<false><<<N_NODES / ROWS, 512, 0, stream>>>(feat, norm, offs, ssrc,
                                                           weight, bias, nullptr, nullptr,
                                                           w_ih, w_hh,
                                                           b_ih, b_hh, out);
    }
}

// Round 11
// 675.174 us; speedup vs baseline: 2.0241x; 2.0241x over previous
//
#include <hip/hip_runtime.h>
#include <hip/hip_bf16.h>
#include <math.h>

#define N_NODES 100000
#define N_EDGES 1600000
#define F 128

// ---------------- ws layout (bytes) ----------------
// deg    : int[100000]      @ 0
// norm   : float[100000]    @ 400000
// offs   : int[100001]      @ 800000
// cursor : int[100000]      @ 1200016   (dead after k_fill -> reused for wihH/L)
// ssrc   : int[1600000]     @ 1600016
// bsum   : int[256]         @ 8000016
// featn  : float[100000*128]@ 8001536
// wihH   : u16[384*128]     @ 1200016   (reuses cursor region AFTER k_fill)
// wihL   : u16[384*128]     @ 1298320
// WtH    : u16[128*128]     @ 59201536
// WtL    : u16[128*128]     @ 59234304
// whhH   : u16[384*128]     @ 59267072
// whhL   : u16[384*128]     @ 59365376
// end 59463680 — within the footprint proven available in R5..R10.

#define WS_FEATN_OFF 8001536
#define WS_WIHH 1200016
#define WS_WIHL 1298320
#define WS_WTH  59201536
#define WS_WTL  59234304
#define WS_WHHH 59267072
#define WS_WHHL 59365376

using s8v = __attribute__((ext_vector_type(8))) short;  // 8 bf16 (4 VGPRs)
using f4v = __attribute__((ext_vector_type(4))) float;  // 4 fp32

// split fp32 x into bf16 hi (RN) + bf16 lo (RN of residual); err ~2^-16 rel
__device__ __forceinline__ void bsplit(float x, unsigned short& h, unsigned short& l) {
    unsigned bx = __float_as_uint(x);
    unsigned rh = bx + 0x7FFFu + ((bx >> 16) & 1u);
    h = (unsigned short)(rh >> 16);
    float fh = __uint_as_float(((unsigned)h) << 16);
    float lo = x - fh;
    unsigned bl = __float_as_uint(lo);
    unsigned rl = bl + 0x7FFFu + ((bl >> 16) & 1u);
    l = (unsigned short)(rl >> 16);
}

__device__ __forceinline__ unsigned long long pack4(unsigned short a, unsigned short b,
                                                    unsigned short c, unsigned short d) {
    return (unsigned long long)a | ((unsigned long long)b << 16) |
           ((unsigned long long)c << 32) | ((unsigned long long)d << 48);
}

// ---------- 1. degree count ----------
__global__ __launch_bounds__(256) void k_degree(const int* __restrict__ dst,
                                                int* __restrict__ deg) {
    int i = blockIdx.x * 256 + threadIdx.x;
    if (i < N_EDGES) atomicAdd(&deg[dst[i]], 1);
}

// ---------- 2. scan ----------
#define SCAN_B 512
#define SCAN_NB 196

__global__ __launch_bounds__(SCAN_B) void k_scan1(const int* __restrict__ deg,
                                                  int* __restrict__ bsum) {
    __shared__ int s[SCAN_B];
    int t = threadIdx.x;
    int i = blockIdx.x * SCAN_B + t;
    s[t] = (i < N_NODES) ? deg[i] : 0;
    __syncthreads();
    for (int o = SCAN_B / 2; o > 0; o >>= 1) {
        if (t < o) s[t] += s[t + o];
        __syncthreads();
    }
    if (t == 0) bsum[blockIdx.x] = s[0];
}

__global__ __launch_bounds__(256) void k_scan2(int* __restrict__ bsum) {
    __shared__ int s[256];
    int t = threadIdx.x;
    int v = (t < SCAN_NB) ? bsum[t] : 0;
    s[t] = v;
    __syncthreads();
    for (int o = 1; o < 256; o <<= 1) {
        int x = (t >= o) ? s[t - o] : 0;
        __syncthreads();
        s[t] += x;
        __syncthreads();
    }
    if (t < SCAN_NB) bsum[t] = (t == 0) ? 0 : s[t - 1];
}

__global__ __launch_bounds__(SCAN_B) void k_scan3(const int* __restrict__ deg,
                                                  const int* __restrict__ bsum,
                                                  int* __restrict__ offs,
                                                  float* __restrict__ norm,
                                                  int* __restrict__ cursor) {
    __shared__ int s[SCAN_B];
    int t = threadIdx.x;
    int i = blockIdx.x * SCAN_B + t;
    int v = (i < N_NODES) ? deg[i] : 0;
    s[t] = v;
    __syncthreads();
    for (int o = 1; o < SCAN_B; o <<= 1) {
        int x = (t >= o) ? s[t - o] : 0;
        __syncthreads();
        s[t] += x;
        __syncthreads();
    }
    if (i < N_NODES) {
        offs[i] = bsum[blockIdx.x] + s[t] - v;
        norm[i] = rsqrtf(fmaxf((float)v, 1.0f));
        cursor[i] = 0;
    }
    if (blockIdx.x == 0 && t == 0) offs[N_NODES] = N_EDGES;
}

// ---------- 3. CSR fill ----------
__global__ __launch_bounds__(256) void k_fill(const int* __restrict__ src,
                                              const int* __restrict__ dst,
                                              const int* __restrict__ offs,
                                              int* __restrict__ cursor,
                                              int* __restrict__ ssrc) {
    int i = blockIdx.x * 256 + threadIdx.x;
    if (i < N_EDGES) {
        int d = dst[i];
        int p = atomicAdd(&cursor[d], 1);
        ssrc[offs[d] + p] = src[i];
    }
}

// ---------- 4. featn = feat * norm[row] ----------
__global__ __launch_bounds__(256) void k_featn(const float* __restrict__ feat,
                                               const float* __restrict__ norm,
                                               float* __restrict__ featn) {
    int idx = blockIdx.x * 256 + threadIdx.x;
    int row = idx >> 5;
    float nv = norm[row];
    float4 v = ((const float4*)feat)[idx];
    v.x *= nv; v.y *= nv; v.z *= nv; v.w *= nv;
    ((float4*)featn)[idx] = v;
}

// ---------- 5. pack weights as bf16 hi/lo ----------
// WtH/L[n][k] = split(weight[k][n])  (transpose: B-frag wants cols of W contiguous in k)
// wihH/L[j][k] = split(w_ih[j][k]);  whhH/L[j][k] = split(w_hh[j][k])
__global__ __launch_bounds__(256) void k_packw(const float* __restrict__ weight,
                                               const float* __restrict__ w_ih,
                                               const float* __restrict__ w_hh,
                                               unsigned short* __restrict__ WtH,
                                               unsigned short* __restrict__ WtL,
                                               unsigned short* __restrict__ wihH,
                                               unsigned short* __restrict__ wihL,
                                               unsigned short* __restrict__ whhH,
                                               unsigned short* __restrict__ whhL) {
    int idx = blockIdx.x * 256 + threadIdx.x;  // 0..114687
    unsigned short h, l;
    if (idx < 16384) {
        int n = idx >> 7, k = idx & 127;
        bsplit(weight[k * 128 + n], h, l);
        WtH[idx] = h; WtL[idx] = l;
    } else if (idx < 65536) {
        int i2 = idx - 16384;
        bsplit(w_ih[i2], h, l);
        wihH[i2] = h; wihL[i2] = l;
    } else {
        int i2 = idx - 65536;
        bsplit(w_hh[i2], h, l);
        whhH[i2] = h; whhL[i2] = l;
    }
}

// ---------- 6. fused gather + MFMA GEMMs + GRU ----------
// ROWS=32, 512 threads (8 waves). Wave w owns output cols [16w,16w+16).
// bf16x2-split MFMA (3 passes HH,HL,LH) for rst-GEMM and GRU gates.
// LDS tiles stored FRAGMENT-MAJOR: elem (mt,row,k) at mt*2048+(k>>3)*128+row*8+(k&7)
// so each A-frag load is a lane-contiguous 1KB wave read (conflict-free).
// k-slot convention (both A and B): slot(g=l>>4, i) <- logical k = 8g+i. Any HW
// k-permutation cancels because A and B use the same slot->k map.
#define ROWS 32
__global__ __launch_bounds__(512, 2) void k_fused(
    const float* __restrict__ featn, const float* __restrict__ norm,
    const int* __restrict__ offs, const int* __restrict__ ssrc,
    const unsigned short* __restrict__ WtH, const unsigned short* __restrict__ WtL,
    const unsigned short* __restrict__ wihH, const unsigned short* __restrict__ wihL,
    const unsigned short* __restrict__ whhH, const unsigned short* __restrict__ whhL,
    const float* __restrict__ bias, const float* __restrict__ b_ih,
    const float* __restrict__ b_hh, float* __restrict__ out) {
    __shared__ __align__(16) unsigned short sfH[4096], sfL[4096];  // featn tile hi/lo
    __shared__ __align__(16) unsigned short sgH[4096], sgL[4096];  // agg tile hi/lo
    __shared__ __align__(16) unsigned short srH[4096], srL[4096];  // rst tile hi/lo
    __shared__ float snorm[ROWS];

    int t = threadIdx.x;
    int l = t & 63, w = t >> 6, g = l >> 4;
    int row0 = blockIdx.x * ROWS;

    if (t < ROWS) snorm[t] = norm[row0 + t];

    // stage featn tile -> bf16 split, fragment-major
#pragma unroll
    for (int u = 0; u < 2; ++u) {
        int idx = u * 512 + t;             // 1024 float4s
        int r = idx >> 5, c = idx & 31;
        float4 f = ((const float4*)(featn + (size_t)(row0 + r) * F))[c];
        int k0 = c * 4;
        int pos = (r >> 4) * 2048 + (k0 >> 3) * 128 + (r & 15) * 8 + (k0 & 7);
        unsigned short h0, l0, h1, l1, h2, l2, h3, l3;
        bsplit(f.x, h0, l0); bsplit(f.y, h1, l1);
        bsplit(f.z, h2, l2); bsplit(f.w, h3, l3);
        *(unsigned long long*)(&sfH[pos]) = pack4(h0, h1, h2, h3);
        *(unsigned long long*)(&sfL[pos]) = pack4(l0, l1, l2, l3);
    }

    // ---- Phase A: gather-sum featn[src] rows -> sgH/sgL ----
    int hf = l >> 5, sub = l & 31;
    for (int ln = w; ln < ROWS; ln += 8) {
        int node = row0 + ln;
        int beg = offs[node], end = offs[node + 1];
        float4 acc = make_float4(0.f, 0.f, 0.f, 0.f);
        int e = beg;
        for (; e + 7 < end; e += 8) {
            int s0 = ssrc[e + 0 + hf];
            int s1 = ssrc[e + 2 + hf];
            int s2 = ssrc[e + 4 + hf];
            int s3 = ssrc[e + 6 + hf];
            float4 v0 = *(const float4*)(featn + (size_t)s0 * F + sub * 4);
            float4 v1 = *(const float4*)(featn + (size_t)s1 * F + sub * 4);
            float4 v2 = *(const float4*)(featn + (size_t)s2 * F + sub * 4);
            float4 v3 = *(const float4*)(featn + (size_t)s3 * F + sub * 4);
            acc.x += (v0.x + v1.x) + (v2.x + v3.x);
            acc.y += (v0.y + v1.y) + (v2.y + v3.y);
            acc.z += (v0.z + v1.z) + (v2.z + v3.z);
            acc.w += (v0.w + v1.w) + (v2.w + v3.w);
        }
        for (; e < end; e += 2) {
            int edge = e + hf;
            if (edge < end) {
                int s0 = ssrc[edge];
                float4 v0 = *(const float4*)(featn + (size_t)s0 * F + sub * 4);
                acc.x += v0.x; acc.y += v0.y; acc.z += v0.z; acc.w += v0.w;
            }
        }
        acc.x += __shfl_xor(acc.x, 32, 64);
        acc.y += __shfl_xor(acc.y, 32, 64);
        acc.z += __shfl_xor(acc.z, 32, 64);
        acc.w += __shfl_xor(acc.w, 32, 64);
        if (hf == 0) {
            int k0 = sub * 4;
            int pos = (ln >> 4) * 2048 + (k0 >> 3) * 128 + (ln & 15) * 8 + (k0 & 7);
            unsigned short h0, l0, h1, l1, h2, l2, h3, l3;
            bsplit(acc.x, h0, l0); bsplit(acc.y, h1, l1);
            bsplit(acc.z, h2, l2); bsplit(acc.w, h3, l3);
            *(unsigned long long*)(&sgH[pos]) = pack4(h0, h1, h2, h3);
            *(unsigned long long*)(&sgL[pos]) = pack4(l0, l1, l2, l3);
        }
    }
    __syncthreads();

    // ---- Phase B: rst = (agg @ W) * norm + bias (MFMA, split 3-pass) ----
    int col = w * 16 + (l & 15);
    f4v cB0 = {0.f, 0.f, 0.f, 0.f}, cB1 = {0.f, 0.f, 0.f, 0.f};
#pragma unroll
    for (int pass = 0; pass < 3; ++pass) {
        const unsigned short* As = (pass < 2) ? sgH : sgL;
        const unsigned short* Bs = (pass == 1) ? WtL : WtH;
#pragma unroll
        for (int s = 0; s < 4; ++s) {
            s8v b = *(const s8v*)(Bs + (size_t)col * 128 + 32 * s + 8 * g);
            s8v a0 = *(const s8v*)(As + s * 512 + l * 8);
            s8v a1 = *(const s8v*)(As + 2048 + s * 512 + l * 8);
            cB0 = __builtin_amdgcn_mfma_f32_16x16x32_bf16(a0, b, cB0, 0, 0, 0);
            cB1 = __builtin_amdgcn_mfma_f32_16x16x32_bf16(a1, b, cB1, 0, 0, 0);
        }
    }
    float bcol = bias[col];
    float rv0[4], rv1[4];
#pragma unroll
    for (int q = 0; q < 4; ++q) {
        int ri = g * 4 + q;
        float v0 = cB0[q] * snorm[ri] + bcol;
        float v1 = cB1[q] * snorm[16 + ri] + bcol;
        rv0[q] = v0; rv1[q] = v1;
        unsigned short hh, ll;
        int posb = (col >> 3) * 128 + ri * 8 + (col & 7);
        bsplit(v0, hh, ll); srH[posb] = hh; srL[posb] = ll;
        bsplit(v1, hh, ll); srH[2048 + posb] = hh; srL[2048 + posb] = ll;
    }
    __syncthreads();

    // ---- Phase C: GRU gates via MFMA (r,z over K=256 concat; i_n, h_n K=128) ----
    f4v ar0 = {0.f,0.f,0.f,0.f}, ar1 = {0.f,0.f,0.f,0.f};
    f4v az0 = {0.f,0.f,0.f,0.f}, az1 = {0.f,0.f,0.f,0.f};
    f4v an0 = {0.f,0.f,0.f,0.f}, an1 = {0.f,0.f,0.f,0.f};
    f4v ah0 = {0.f,0.f,0.f,0.f}, ah1 = {0.f,0.f,0.f,0.f};
#pragma unroll
    for (int pass = 0; pass < 3; ++pass) {
        const unsigned short* AF = (pass < 2) ? sfH : sfL;
        const unsigned short* AR = (pass < 2) ? srH : srL;
        const unsigned short* WI = (pass == 1) ? wihL : wihH;
        const unsigned short* WH = (pass == 1) ? whhL : whhH;
#pragma unroll
        for (int s = 0; s < 4; ++s) {
            int koff = 32 * s + 8 * g;
            s8v bir = *(const s8v*)(WI + (size_t)col * 128 + koff);
            s8v biz = *(const s8v*)(WI + (size_t)(col + 128) * 128 + koff);
            s8v bin = *(const s8v*)(WI + (size_t)(col + 256) * 128 + koff);
            s8v bhr = *(const s8v*)(WH + (size_t)col * 128 + koff);
            s8v bhz = *(const s8v*)(WH + (size_t)(col + 128) * 128 + koff);
            s8v bhn = *(const s8v*)(WH + (size_t)(col + 256) * 128 + koff);
            s8v f0 = *(const s8v*)(AF + s * 512 + l * 8);
            s8v f1 = *(const s8v*)(AF + 2048 + s * 512 + l * 8);
            s8v r0 = *(const s8v*)(AR + s * 512 + l * 8);
            s8v r1 = *(const s8v*)(AR + 2048 + s * 512 + l * 8);
            ar0 = __builtin_amdgcn_mfma_f32_16x16x32_bf16(f0, bir, ar0, 0, 0, 0);
            ar0 = __builtin_amdgcn_mfma_f32_16x16x32_bf16(r0, bhr, ar0, 0, 0, 0);
            ar1 = __builtin_amdgcn_mfma_f32_16x16x32_bf16(f1, bir, ar1, 0, 0, 0);
            ar1 = __builtin_amdgcn_mfma_f32_16x16x32_bf16(r1, bhr, ar1, 0, 0, 0);
            az0 = __builtin_amdgcn_mfma_f32_16x16x32_bf16(f0, biz, az0, 0, 0, 0);
            az0 = __builtin_amdgcn_mfma_f32_16x16x32_bf16(r0, bhz, az0, 0, 0, 0);
            az1 = __builtin_amdgcn_mfma_f32_16x16x32_bf16(f1, biz, az1, 0, 0, 0);
            az1 = __builtin_amdgcn_mfma_f32_16x16x32_bf16(r1, bhz, az1, 0, 0, 0);
            an0 = __builtin_amdgcn_mfma_f32_16x16x32_bf16(f0, bin, an0, 0, 0, 0);
            an1 = __builtin_amdgcn_mfma_f32_16x16x32_bf16(f1, bin, an1, 0, 0, 0);
            ah0 = __builtin_amdgcn_mfma_f32_16x16x32_bf16(r0, bhn, ah0, 0, 0, 0);
            ah1 = __builtin_amdgcn_mfma_f32_16x16x32_bf16(r1, bhn, ah1, 0, 0, 0);
        }
    }

    // ---- epilogue: gates + blend ----
    float Bir = b_ih[col], Bhr = b_hh[col];
    float Biz = b_ih[col + 128], Bhz = b_hh[col + 128];
    float Bin = b_ih[col + 256], Bhn = b_hh[col + 256];
#pragma unroll
    for (int q = 0; q < 4; ++q) {
        int ri = g * 4 + q;
        {
            float rr = 1.0f / (1.0f + __expf(-(ar0[q] + Bir + Bhr)));
            float zz = 1.0f / (1.0f + __expf(-(az0[q] + Biz + Bhz)));
            float nn = tanhf(an0[q] + Bin + rr * (ah0[q] + Bhn));
            out[(size_t)(row0 + ri) * F + col] = (1.0f - zz) * nn + zz * rv0[q];
        }
        {
            float rr = 1.0f / (1.0f + __expf(-(ar1[q] + Bir + Bhr)));
            float zz = 1.0f / (1.0f + __expf(-(az1[q] + Biz + Bhz)));
            float nn = tanhf(an1[q] + Bin + rr * (ah1[q] + Bhn));
            out[(size_t)(row0 + 16 + ri) * F + col] = (1.0f - zz) * nn + zz * rv1[q];
        }
    }
}

extern "C" void kernel_launch(void* const* d_in, const int* in_sizes, int n_in,
                              void* d_out, int out_size, void* d_ws, size_t ws_size,
                              hipStream_t stream) {
    const float* feat   = (const float*)d_in[0];
    const float* weight = (const float*)d_in[1];
    const float* bias   = (const float*)d_in[2];
    const float* w_ih   = (const float*)d_in[3];
    const float* w_hh   = (const float*)d_in[4];
    const float* b_ih   = (const float*)d_in[5];
    const float* b_hh   = (const float*)d_in[6];
    const int*   src    = (const int*)d_in[7];
    const int*   dst    = (const int*)d_in[8];
    float* out = (float*)d_out;

    char* ws = (char*)d_ws;
    int*   deg    = (int*)(ws + 0);
    float* norm   = (float*)(ws + 400000);
    int*   offs   = (int*)(ws + 800000);
    int*   cursor = (int*)(ws + 1200016);
    int*   ssrc   = (int*)(ws + 1600016);
    int*   bsum   = (int*)(ws + 8000016);
    float* featn  = (float*)(ws + WS_FEATN_OFF);
    unsigned short* wihH = (unsigned short*)(ws + WS_WIHH);  // overlays cursor (dead)
    unsigned short* wihL = (unsigned short*)(ws + WS_WIHL);
    unsigned short* WtH  = (unsigned short*)(ws + WS_WTH);
    unsigned short* WtL  = (unsigned short*)(ws + WS_WTL);
    unsigned short* whhH = (unsigned short*)(ws + WS_WHHH);
    unsigned short* whhL = (unsigned short*)(ws + WS_WHHL);

    hipMemsetAsync(deg, 0, N_NODES * sizeof(int), stream);

    k_degree<<<(N_EDGES + 255) / 256, 256, 0, stream>>>(dst, deg);
    k_scan1<<<SCAN_NB, SCAN_B, 0, stream>>>(deg, bsum);
    k_scan2<<<1, 256, 0, stream>>>(bsum);
    k_scan3<<<SCAN_NB, SCAN_B, 0, stream>>>(deg, bsum, offs, norm, cursor);
    k_fill<<<(N_EDGES + 255) / 256, 256, 0, stream>>>(src, dst, offs, cursor, ssrc);
    // after k_fill, cursor region is dead -> k_packw may overwrite it with wihH/L
    k_packw<<<448, 256, 0, stream>>>(weight, w_ih, w_hh, WtH, WtL, wihH, wihL, whhH, whhL);
    k_featn<<<(N_NODES * F / 4) / 256, 256, 0, stream>>>(feat, norm, featn);
    k_fused<<<N_NODES / ROWS, 512, 0, stream>>>(featn, norm, offs, ssrc,
                                                WtH, WtL, wihH, wihL, whhH, whhL,
                                                bias, b_ih, b_hh, out);
}